// Round 10
// baseline (762.381 us; speedup 1.0000x reference)
//
#include <hip/hip_runtime.h>
#include <hip/hip_bf16.h>
#include <cstdint>

constexpr int NB = 256;   // batch
constexpr int NT = 512;   // frames
constexpr int ND = 512;   // dim

typedef __attribute__((ext_vector_type(8))) short bf16x8;
typedef __attribute__((ext_vector_type(4))) float f32x4;
typedef __attribute__((ext_vector_type(2))) unsigned int u32x2;

__device__ __forceinline__ float wred_sum(float v){
#pragma unroll
  for (int m = 32; m > 0; m >>= 1) v += __shfl_xor(v, m, 64);
  return v;
}
// f32 -> bf16 round-to-nearest-even
__device__ __forceinline__ unsigned int f2bf(float f){
  unsigned int u = __builtin_bit_cast(unsigned int, f);
  u = u + 0x7fffu + ((u >> 16) & 1u);
  return (u >> 16);
}
// async global->LDS, 16B per lane
__device__ __forceinline__ void gload_lds16(const void* g, void* l){
  __builtin_amdgcn_global_load_lds(
      (const __attribute__((address_space(1))) unsigned int*)g,
      (__attribute__((address_space(3))) unsigned int*)l, 16, 0, 0);
}

// K0: sentence norms -> normalized bf16 rows
__global__ __launch_bounds__(256) void k_sent(const float* __restrict__ s,
                                              unsigned short* __restrict__ sb){
  int row  = blockIdx.x * 4 + (threadIdx.x >> 6);
  int lane = threadIdx.x & 63;
  const float* sr = s + (size_t)row * ND;
  float x[8]; float ss = 0.f;
#pragma unroll
  for (int e = 0; e < 8; e++){ x[e] = sr[lane + e*64]; ss += x[e]*x[e]; }
  ss = wred_sum(ss);
  float inv = 1.0f / fmaxf(sqrtf(ss), 1e-8f);
#pragma unroll
  for (int e = 0; e < 8; e++)
    sb[(size_t)row*ND + lane + e*64] = (unsigned short)f2bf(x[e]*inv);
}

// Fused single-video-read kernel:
//  H ring-3 (f32 halves, 2 in flight) -> conflict-free convert (read-as-staged)
//  -> TB bf16 (XOR-slotted, single buf) -> MFMA -> fused softmax + store.
// 64j x 512t per block, one b. Exact per-wave vmcnt ledger; raw barriers only.
__global__ __launch_bounds__(512, 1) void k_fused(
    const unsigned short* __restrict__ sb,   // normalized sentences bf16
    const float* __restrict__ video,         // raw f32 video
    const float* __restrict__ sent,          // raw f32 sentences
    const int* __restrict__ lens,
    float* __restrict__ out0,
    float* __restrict__ diag){
  const int tid  = threadIdx.x;
  const int lane = tid & 63;
  const int w    = tid >> 6;
  const int wj   = w >> 2;      // 0..1
  const int wt   = w & 3;       // 0..3
  const int q    = tid & 3;

  // XCD-grouped decode: 4 j-tile blocks of one b share (blockIdx & 7)
  const int D  = blockIdx.x;
  const int x8 = D & 7;
  const int r0 = D >> 3;
  const int s  = r0 & 3;        // j-tile 0..3
  const int b  = (r0 >> 2) * 8 + x8;
  const int jt = s * 64;

  // pool: H f32 ring [3][32768] @0 | TB bf16 [512][64B] @98304 | A [2][4096] @131072
  __shared__ __align__(16) char pool[139264];
  __shared__ float sRowS[ND];
  __shared__ float vinvS[NT];
  __shared__ float redM[64*4];
  __shared__ float redS[64*4];

  sRowS[tid] = sent[(size_t)b*ND + tid];

  // B-stage: wave w rows w*64+i*16+(lane>>2), chunk lane&3 (dest linear)
  const float* vstage = video + ((size_t)(b*NT + w*64 + (lane>>2)))*ND + (lane&3)*4;
  // A-stage (waves 0-3), pre-swizzled source matching goffA
  const unsigned short* asrc =
      sb + (size_t)(jt + (w&3)*16 + (lane>>2))*ND + ((lane&3)^((lane>>3)&3))*8;

  const int rl = lane & 15;
  const int gr = lane >> 4;
  const int goffA = ((gr ^ ((rl>>1)&3)) << 4);

  f32x4 acc[2][8] = {};
  float pssq[4] = {}, pdp[4] = {};

#define STAGE_B(h) {                                                            \
  _Pragma("unroll") for (int i = 0; i < 4; i++)                                 \
    gload_lds16(vstage + (size_t)i*16*ND + (h)*16,                              \
                pool + ((h)%3)*32768 + w*4096 + i*1024 + lane*16); }

#define STAGE_A(m) { if (w < 4)                                                 \
    gload_lds16(asrc + (m)*32, pool + 131072 + ((m)&1)*4096 + w*1024 + lane*16); }

// conflict-free convert: thread reads its staged 16B stripes (contiguous per
// quarter-wave); owns chunk q of rows (tid>>2)+128i; TB write XOR-slotted.
#define CONVERT(h) {                                                            \
  f32x4 sc = *(const f32x4*)(sRowS + (h)*16 + q*4);                             \
  const char* hp = pool + ((h)%3)*32768 + tid*16;                               \
  char* tb = pool + 98304;                                                      \
  _Pragma("unroll") for (int i2 = 0; i2 < 4; i2++){                             \
    f32x4 x = *(const f32x4*)(hp + i2*8192);                                    \
    pssq[i2] += x[0]*x[0] + x[1]*x[1] + x[2]*x[2] + x[3]*x[3];                  \
    pdp[i2]  += x[0]*sc[0] + x[1]*sc[1] + x[2]*sc[2] + x[3]*sc[3];              \
    u32x2 pk;                                                                   \
    pk[0] = f2bf(x[0]) | (f2bf(x[1]) << 16);                                    \
    pk[1] = f2bf(x[2]) | (f2bf(x[3]) << 16);                                    \
    const int r_  = i2*128 + (tid>>2);                                          \
    const int sl_ = ((((h)&1)<<2) + q) ^ (r_ & 6);                              \
    *(u32x2*)(tb + r_*64 + sl_*8) = pk; } }

#define MFMA_PHASE(m) {                                                         \
  const char* Ab = pool + 131072 + ((m)&1)*4096;                                \
  const char* Bb = pool + 98304;                                                \
  bf16x8 af0 = *(const bf16x8*)(Ab + (wj*32 +      rl)*64 + goffA);             \
  bf16x8 af1 = *(const bf16x8*)(Ab + (wj*32 + 16 + rl)*64 + goffA);             \
  bf16x8 bgv[8];                                                                \
  _Pragma("unroll") for (int fj = 0; fj < 8; fj++){                             \
    int t_ = wt*128 + fj*16 + rl;                                               \
    bgv[fj] = *(const bf16x8*)(Bb + t_*64 + (((2*gr) ^ (t_&6)) << 3)); }        \
  asm volatile("s_waitcnt lgkmcnt(0)" ::: "memory");                            \
  __builtin_amdgcn_sched_barrier(0);                                            \
  __builtin_amdgcn_s_barrier();                                                 \
  __builtin_amdgcn_sched_barrier(0);                                            \
  _Pragma("unroll") for (int fj = 0; fj < 8; fj++){                             \
    acc[0][fj] = __builtin_amdgcn_mfma_f32_16x16x32_bf16(af0, bgv[fj], acc[0][fj], 0,0,0); \
    acc[1][fj] = __builtin_amdgcn_mfma_f32_16x16x32_bf16(af1, bgv[fj], acc[1][fj], 0,0,0); } \
  __builtin_amdgcn_sched_barrier(0); }

#define HALF(h, VA, VB, ...) {                                                  \
  if (w < 4) { asm volatile("s_waitcnt vmcnt(" VA ")" ::: "memory"); }          \
  else       { asm volatile("s_waitcnt vmcnt(" VB ")" ::: "memory"); }          \
  __builtin_amdgcn_sched_barrier(0);                                            \
  __builtin_amdgcn_s_barrier();                                                 \
  __builtin_amdgcn_sched_barrier(0);                                            \
  CONVERT(h)                                                                    \
  asm volatile("s_waitcnt lgkmcnt(0)" ::: "memory");                            \
  __builtin_amdgcn_sched_barrier(0);                                            \
  __builtin_amdgcn_s_barrier();                                                 \
  __builtin_amdgcn_sched_barrier(0);                                            \
  __VA_ARGS__                                                                   \
  __builtin_amdgcn_sched_barrier(0); }

  // prologue (issue order fixes the vmcnt ledger: B0,A0,B1,B2,A1)
  STAGE_B(0); STAGE_A(0); STAGE_B(1); STAGE_B(2); STAGE_A(1);
  asm volatile("s_waitcnt lgkmcnt(0)" ::: "memory");   // sRowS visible
  __builtin_amdgcn_sched_barrier(0);
  __builtin_amdgcn_s_barrier();
  __builtin_amdgcn_sched_barrier(0);

#pragma unroll
  for (int m = 0; m < 14; ++m){
    HALF(2*m,     "9", "8", STAGE_B(2*m+3);)
    HALF(2*m + 1, "9", "8", STAGE_B(2*m+4); STAGE_A(m+2);)
    MFMA_PHASE(m)
  }
  // m = 14
  HALF(28, "9", "8", STAGE_B(31);)
  HALF(29, "9", "8", )
  MFMA_PHASE(14)
  // m = 15 (drain)
  HALF(30, "4", "4", )
  HALF(31, "0", "0", )
  MFMA_PHASE(15)

#undef HALF
#undef MFMA_PHASE
#undef CONVERT
#undef STAGE_A
#undef STAGE_B

  // ---- reduce ssq/dp across the 4 q-lanes; thread owns row (tid>>2)+128q ----
#pragma unroll
  for (int i = 0; i < 4; i++){
#pragma unroll
    for (int msk = 1; msk <= 2; msk <<= 1){
      pssq[i] += __shfl_xor(pssq[i], msk, 64);
      pdp[i]  += __shfl_xor(pdp[i],  msk, 64);
    }
  }
  float myssq = (q==0) ? pssq[0] : (q==1) ? pssq[1] : (q==2) ? pssq[2] : pssq[3];
  float mydp  = (q==0) ? pdp[0]  : (q==1) ? pdp[1]  : (q==2) ? pdp[2]  : pdp[3];
  {
    const int myrow = (tid>>2) + 128*q;
    float inv = 1.0f / fmaxf(sqrtf(myssq), 1e-8f);
    vinvS[myrow] = inv;
    if (s == 0) diag[(size_t)b*NT + myrow] = mydp * inv;  // sent-norm factor
  }                                                       // dropped (argmax-inv)
  __syncthreads();

  // ---- masked softmax over t (apply vinv to accumulator here) ----
  const int len = lens[b];
  const int tl = rl;
  const float NEGINF = -__builtin_inff();

  float mx[2][4];
#pragma unroll
  for (int fi = 0; fi < 2; fi++)
#pragma unroll
    for (int rr = 0; rr < 4; rr++) mx[fi][rr] = NEGINF;

#pragma unroll
  for (int fi = 0; fi < 2; fi++)
#pragma unroll
    for (int fj = 0; fj < 8; fj++){
      int t = wt*128 + fj*16 + tl;
      float vi = vinvS[t];
      bool ok = t < len;
#pragma unroll
      for (int rr = 0; rr < 4; rr++){
        float v = ok ? acc[fi][fj][rr]*vi : NEGINF;
        acc[fi][fj][rr] = v;
        mx[fi][rr] = fmaxf(mx[fi][rr], v);
      }
    }
#pragma unroll
  for (int fi = 0; fi < 2; fi++)
#pragma unroll
    for (int rr = 0; rr < 4; rr++)
#pragma unroll
      for (int msk = 1; msk <= 8; msk <<= 1)
        mx[fi][rr] = fmaxf(mx[fi][rr], __shfl_xor(mx[fi][rr], msk, 64));
  if (tl == 0){
#pragma unroll
    for (int fi = 0; fi < 2; fi++)
#pragma unroll
      for (int rr = 0; rr < 4; rr++)
        redM[(wj*32 + fi*16 + gr*4 + rr)*4 + wt] = mx[fi][rr];
  }
  __syncthreads();

  float gmx[2][4], sum[2][4];
#pragma unroll
  for (int fi = 0; fi < 2; fi++)
#pragma unroll
    for (int rr = 0; rr < 4; rr++){
      int jl = wj*32 + fi*16 + gr*4 + rr;
      gmx[fi][rr] = fmaxf(fmaxf(redM[jl*4+0], redM[jl*4+1]),
                          fmaxf(redM[jl*4+2], redM[jl*4+3]));
      sum[fi][rr] = 0.f;
    }
#pragma unroll
  for (int fi = 0; fi < 2; fi++)
#pragma unroll
    for (int fj = 0; fj < 8; fj++)
#pragma unroll
      for (int rr = 0; rr < 4; rr++){
        float e = __expf(acc[fi][fj][rr] - gmx[fi][rr]);  // exp(-inf)=0 masked
        acc[fi][fj][rr] = e;
        sum[fi][rr] += e;
      }
#pragma unroll
  for (int fi = 0; fi < 2; fi++)
#pragma unroll
    for (int rr = 0; rr < 4; rr++)
#pragma unroll
      for (int msk = 1; msk <= 8; msk <<= 1)
        sum[fi][rr] += __shfl_xor(sum[fi][rr], msk, 64);
  if (tl == 0){
#pragma unroll
    for (int fi = 0; fi < 2; fi++)
#pragma unroll
      for (int rr = 0; rr < 4; rr++)
        redS[(wj*32 + fi*16 + gr*4 + rr)*4 + wt] = sum[fi][rr];
  }
  __syncthreads();

  float ivv[2][4];
#pragma unroll
  for (int fi = 0; fi < 2; fi++)
#pragma unroll
    for (int rr = 0; rr < 4; rr++){
      int jl = wj*32 + fi*16 + gr*4 + rr;
      ivv[fi][rr] = 1.0f / ((redS[jl*4+0] + redS[jl*4+1]) + (redS[jl*4+2] + redS[jl*4+3]));
    }

  // ---- coalesced store via LDS transpose (reuse pool: 32 x 516 f32) ----
  float* pf = (float*)pool;
  const int r2 = tid >> 7;
  const int c4 = (tid & 127) * 4;
#pragma unroll
  for (int fi = 0; fi < 2; fi++){
    __syncthreads();
#pragma unroll
    for (int fj = 0; fj < 8; fj++){
      int t = wt*128 + fj*16 + tl;
#pragma unroll
      for (int rr = 0; rr < 4; rr++){
        int r = wj*16 + gr*4 + rr;
        pf[r*516 + t] = acc[fi][fj][rr] * ivv[fi][rr];
      }
    }
    __syncthreads();
#pragma unroll
    for (int p = 0; p < 8; p++){
      int row = p*4 + r2;
      int gj  = jt + ((row >> 4) * 32) + fi*16 + (row & 15);
      f32x4 vv = *reinterpret_cast<const f32x4*>(pf + row*516 + c4);
      *reinterpret_cast<f32x4*>(out0 + ((size_t)b*NB + gj)*NT + c4) = vv;
    }
  }
}

// argmax over valid t of diag (first-index tie-break) + copy chosen frame row
__global__ __launch_bounds__(256) void k_argmax(const float* __restrict__ video,
                                                const int* __restrict__ lens,
                                                const float* __restrict__ diag,
                                                float* __restrict__ o1){
  int b = blockIdx.x;
  int tid = threadIdx.x;
  int len = lens[b];
  __shared__ float sv[256];
  __shared__ int   si[256];
  const float* dg = diag + (size_t)b * NT;
  float v1 = (tid       < len) ? dg[tid]       : -__builtin_inff();
  float v2 = (tid + 256 < len) ? dg[tid + 256] : -__builtin_inff();
  float bv; int bi;
  if (v2 > v1){ bv = v2; bi = tid + 256; } else { bv = v1; bi = tid; }
  sv[tid] = bv; si[tid] = bi;
  __syncthreads();
  for (int sN = 128; sN > 0; sN >>= 1){
    if (tid < sN){
      float ov = sv[tid+sN]; int oi = si[tid+sN];
      if (ov > sv[tid] || (ov == sv[tid] && oi < si[tid])){ sv[tid] = ov; si[tid] = oi; }
    }
    __syncthreads();
  }
  int best = si[0];
  const float* src = video + ((size_t)b * NT + best) * ND;
  o1[(size_t)b * ND + tid]       = src[tid];
  o1[(size_t)b * ND + tid + 256] = src[tid + 256];
}

extern "C" void kernel_launch(void* const* d_in, const int* in_sizes, int n_in,
                              void* d_out, int out_size, void* d_ws, size_t ws_size,
                              hipStream_t stream){
  const float* video = (const float*)d_in[0];
  const float* sent  = (const float*)d_in[1];
  const int*   lens  = (const int*)d_in[2];
  float* out0 = (float*)d_out;
  float* out1 = out0 + (size_t)NB*NB*NT;

  char* ws = (char*)d_ws;
  unsigned short* sb = (unsigned short*)ws;      // 262144 B
  float* diagw = (float*)(ws + 262144);          // 524288 B

  k_sent  <<<NB/4, 256, 0, stream>>>(sent, sb);
  k_fused <<<NB*4, 512, 0, stream>>>(sb, video, sent, lens, out0, diagw);
  k_argmax<<<NB,   256, 0, stream>>>(video, lens, diagw, out1);
}

// Round 11
// 169.376 us; speedup vs baseline: 4.5011x; 4.5011x over previous
//
#include <hip/hip_runtime.h>
#include <hip/hip_bf16.h>
#include <cstdint>

constexpr int NB = 256;   // batch
constexpr int NT = 512;   // frames
constexpr int ND = 512;   // dim

typedef __attribute__((ext_vector_type(8))) short bf16x8;
typedef __attribute__((ext_vector_type(4))) float f32x4;
typedef __attribute__((ext_vector_type(4))) unsigned int u32x4;

__device__ __forceinline__ float wred_sum(float v){
#pragma unroll
  for (int m = 32; m > 0; m >>= 1) v += __shfl_xor(v, m, 64);
  return v;
}
// f32 -> bf16 round-to-nearest-even
__device__ __forceinline__ unsigned int f2bf(float f){
  unsigned int u = __builtin_bit_cast(unsigned int, f);
  u = u + 0x7fffu + ((u >> 16) & 1u);
  return (u >> 16);
}
// async global->LDS, 16B per lane (dest: lane0's addr = wave base, HW adds lane*16)
__device__ __forceinline__ void gload_lds16(const void* g, void* l){
  __builtin_amdgcn_global_load_lds(
      (const __attribute__((address_space(1))) unsigned int*)g,
      (__attribute__((address_space(3))) unsigned int*)l, 16, 0, 0);
}

// K0: sentence norms -> normalized bf16 rows
__global__ __launch_bounds__(256) void k_sent(const float* __restrict__ s,
                                              unsigned short* __restrict__ sb){
  int row  = blockIdx.x * 4 + (threadIdx.x >> 6);
  int lane = threadIdx.x & 63;
  const float* sr = s + (size_t)row * ND;
  float x[8]; float ss = 0.f;
#pragma unroll
  for (int e = 0; e < 8; e++){ x[e] = sr[lane + e*64]; ss += x[e]*x[e]; }
  ss = wred_sum(ss);
  float inv = 1.0f / fmaxf(sqrtf(ss), 1e-8f);
#pragma unroll
  for (int e = 0; e < 8; e++)
    sb[(size_t)row*ND + lane + e*64] = (unsigned short)f2bf(x[e]*inv);
}

// K1: stream video once: per (b,t) row compute 1/norm + diag ranking value
// (dp*inv; sentence-norm factor dropped — positive per-b constant, argmax-
// invariant), write normalized bf16 video row. One wave per row, 4 rows/block.
// Sentence chunk read directly from global (L2-resident, same offsets as the
// video chunk) — no LDS staging, no barrier.
__global__ __launch_bounds__(256) void k_vnorm(const float* __restrict__ video,
                                               const float* __restrict__ sent,
                                               unsigned short* __restrict__ vb16,
                                               float* __restrict__ diag){
  const int tid  = threadIdx.x;
  const int row  = blockIdx.x * 4 + (tid >> 6);   // b*512 + t  (block-uniform b)
  const int lane = tid & 63;
  const int b    = row >> 9;

  const float* vr = video + (size_t)row * ND;
  const float* sr = sent  + (size_t)b   * ND;
  f32x4 x0 = *reinterpret_cast<const f32x4*>(vr + lane*8);
  f32x4 x1 = *reinterpret_cast<const f32x4*>(vr + lane*8 + 4);
  f32x4 s0 = *reinterpret_cast<const f32x4*>(sr + lane*8);
  f32x4 s1 = *reinterpret_cast<const f32x4*>(sr + lane*8 + 4);
  float ss = 0.f, dp = 0.f;
#pragma unroll
  for (int i = 0; i < 4; i++){
    ss += x0[i]*x0[i] + x1[i]*x1[i];
    dp += x0[i]*s0[i] + x1[i]*s1[i];
  }
#pragma unroll
  for (int m = 32; m > 0; m >>= 1){
    ss += __shfl_xor(ss, m, 64);
    dp += __shfl_xor(dp, m, 64);
  }
  float inv = 1.0f / fmaxf(sqrtf(ss), 1e-8f);
  if (lane == 0) diag[row] = dp * inv;
  u32x4 d;
  d[0] = f2bf(x0[0]*inv) | (f2bf(x0[1]*inv) << 16);
  d[1] = f2bf(x0[2]*inv) | (f2bf(x0[3]*inv) << 16);
  d[2] = f2bf(x1[0]*inv) | (f2bf(x1[1]*inv) << 16);
  d[3] = f2bf(x1[2]*inv) | (f2bf(x1[3]*inv) << 16);
  *reinterpret_cast<u32x4*>(vb16 + (size_t)row*ND + lane*8) = d;
}

// K2: pure bf16 GEMM (64j x 512t per block, one b) + fused masked softmax.
// global_load_lds staging (swizzled global source, rule-21 both-sides XOR),
// double-buffered LDS, BK=32, 2-phase pipeline, 8 waves (2j x 4t).
// (r4-proven 169 µs version, byte-identical.)
__global__ __launch_bounds__(512, 4) void k_gemm_sm(
    const unsigned short* __restrict__ sb,     // normalized sentences bf16
    const unsigned short* __restrict__ vb16,   // normalized video bf16
    const int* __restrict__ lens,
    float* __restrict__ out0){
  const int tid  = threadIdx.x;
  const int lane = tid & 63;
  const int w    = tid >> 6;
  const int wj   = w >> 2;      // 0..1
  const int wt   = w & 3;       // 0..3

  // XCD-grouped decode: the 4 j-tile blocks of one b share (blockIdx & 7)
  const int D  = blockIdx.x;
  const int x8 = D & 7;
  const int r0 = D >> 3;
  const int s  = r0 & 3;        // j-tile 0..3
  const int b  = (r0 >> 2) * 8 + x8;
  const int jt = s * 64;

  __shared__ __align__(16) unsigned short As[2][64*32];    //  8 KB
  __shared__ __align__(16) unsigned short Bs[2][NT*32];    // 64 KB
  __shared__ float redM[64*4];                             //  1 KB
  __shared__ float redS[64*4];                             //  1 KB

  const unsigned short* vbase = vb16 + (size_t)b * NT * ND;
  // staging: lane's LDS granule (lane&3); fetched global granule (lane&3)^((lane>>3)&3)
  const int srow = lane >> 2;
  const int sgr  = ((lane&3) ^ ((lane>>3)&3)) * 8;

  char* AsB = (char*)As;
  char* BsB = (char*)Bs;

  auto STAGE = [&](int buf, int k0){
#pragma unroll
    for (int i = 0; i < 4; i++){
      int grow = w*64 + i*16 + srow;                  // t-row
      gload_lds16(vbase + (size_t)grow*ND + k0 + sgr,
                  BsB + buf*32768 + w*4096 + i*1024 + lane*16);
    }
    if (w < 4){
      int grow = jt + w*16 + srow;                    // j-row
      gload_lds16(sb + (size_t)grow*ND + k0 + sgr,
                  AsB + buf*4096 + w*1024 + lane*16);
    }
  };

  f32x4 acc[2][8] = {};

  STAGE(0, 0);
  asm volatile("s_waitcnt vmcnt(0)" ::: "memory");
  __syncthreads();

  const int rl = lane & 15;
  const int gr = lane >> 4;
  const int goff = ((gr ^ ((rl>>1)&3)) << 4);   // swizzled byte offset of k-granule

  for (int k = 0; k < 16; ++k){
    const int cur = k & 1;
    if (k < 15) STAGE(1-cur, (k+1)*32);
    __builtin_amdgcn_sched_barrier(0);   // keep STAGE issue above the compute phase

    bf16x8 af0 = *reinterpret_cast<const bf16x8*>(AsB + cur*4096 + (wj*32 +      rl)*64 + goff);
    bf16x8 af1 = *reinterpret_cast<const bf16x8*>(AsB + cur*4096 + (wj*32 + 16 + rl)*64 + goff);
#pragma unroll
    for (int fj = 0; fj < 8; fj++){
      bf16x8 bg = *reinterpret_cast<const bf16x8*>(BsB + cur*32768 + (wt*128 + fj*16 + rl)*64 + goff);
      acc[0][fj] = __builtin_amdgcn_mfma_f32_16x16x32_bf16(af0, bg, acc[0][fj], 0, 0, 0);
      acc[1][fj] = __builtin_amdgcn_mfma_f32_16x16x32_bf16(af1, bg, acc[1][fj], 0, 0, 0);
    }
    asm volatile("s_waitcnt vmcnt(0)" ::: "memory");
    __syncthreads();
  }

  // ---- masked softmax over t (full 512 per j-row); acc IS cosine sim ----
  const int len = lens[b];
  const int q  = gr;
  const int tl = rl;
  const float NEGINF = -__builtin_inff();

  float mx[2][4];
#pragma unroll
  for (int fi = 0; fi < 2; fi++)
#pragma unroll
    for (int rr = 0; rr < 4; rr++) mx[fi][rr] = NEGINF;

#pragma unroll
  for (int fi = 0; fi < 2; fi++)
#pragma unroll
    for (int fj = 0; fj < 8; fj++){
      int t = wt*128 + fj*16 + tl;
      bool ok = t < len;
#pragma unroll
      for (int rr = 0; rr < 4; rr++){
        float v = ok ? acc[fi][fj][rr] : NEGINF;
        acc[fi][fj][rr] = v;
        mx[fi][rr] = fmaxf(mx[fi][rr], v);
      }
    }
#pragma unroll
  for (int fi = 0; fi < 2; fi++)
#pragma unroll
    for (int rr = 0; rr < 4; rr++)
#pragma unroll
      for (int msk = 1; msk <= 8; msk <<= 1)
        mx[fi][rr] = fmaxf(mx[fi][rr], __shfl_xor(mx[fi][rr], msk, 64));
  if (tl == 0){
#pragma unroll
    for (int fi = 0; fi < 2; fi++)
#pragma unroll
      for (int rr = 0; rr < 4; rr++)
        redM[(wj*32 + fi*16 + q*4 + rr)*4 + wt] = mx[fi][rr];
  }
  __syncthreads();

  float gmx[2][4], sum[2][4];
#pragma unroll
  for (int fi = 0; fi < 2; fi++)
#pragma unroll
    for (int rr = 0; rr < 4; rr++){
      int jl = wj*32 + fi*16 + q*4 + rr;
      gmx[fi][rr] = fmaxf(fmaxf(redM[jl*4+0], redM[jl*4+1]),
                          fmaxf(redM[jl*4+2], redM[jl*4+3]));
      sum[fi][rr] = 0.f;
    }
#pragma unroll
  for (int fi = 0; fi < 2; fi++)
#pragma unroll
    for (int fj = 0; fj < 8; fj++)
#pragma unroll
      for (int rr = 0; rr < 4; rr++){
        float e = __expf(acc[fi][fj][rr] - gmx[fi][rr]);  // exp(-inf)=0 for masked
        acc[fi][fj][rr] = e;
        sum[fi][rr] += e;
      }
#pragma unroll
  for (int fi = 0; fi < 2; fi++)
#pragma unroll
    for (int rr = 0; rr < 4; rr++)
#pragma unroll
      for (int msk = 1; msk <= 8; msk <<= 1)
        sum[fi][rr] += __shfl_xor(sum[fi][rr], msk, 64);
  if (tl == 0){
#pragma unroll
    for (int fi = 0; fi < 2; fi++)
#pragma unroll
      for (int rr = 0; rr < 4; rr++)
        redS[(wj*32 + fi*16 + q*4 + rr)*4 + wt] = sum[fi][rr];
  }
  __syncthreads();

#pragma unroll
  for (int fi = 0; fi < 2; fi++)
#pragma unroll
    for (int rr = 0; rr < 4; rr++){
      int jl = wj*32 + fi*16 + q*4 + rr;
      float tot = (redS[jl*4+0] + redS[jl*4+1]) + (redS[jl*4+2] + redS[jl*4+3]);
      float iv = 1.0f / tot;
      int j = jt + jl;
      float* orow = out0 + ((size_t)b*NB + j)*NT + wt*128 + tl;
#pragma unroll
      for (int fj = 0; fj < 8; fj++)
        orow[fj*16] = acc[fi][fj][rr]*iv;
    }
}

// argmax over valid t of diag (first-index tie-break) + copy chosen frame row
__global__ __launch_bounds__(256) void k_argmax(const float* __restrict__ video,
                                                const int* __restrict__ lens,
                                                const float* __restrict__ diag,
                                                float* __restrict__ o1){
  int b = blockIdx.x;
  int tid = threadIdx.x;
  int len = lens[b];
  __shared__ float sv[256];
  __shared__ int   si[256];
  const float* dg = diag + (size_t)b * NT;
  float v1 = (tid       < len) ? dg[tid]       : -__builtin_inff();
  float v2 = (tid + 256 < len) ? dg[tid + 256] : -__builtin_inff();
  float bv; int bi;
  if (v2 > v1){ bv = v2; bi = tid + 256; } else { bv = v1; bi = tid; }
  sv[tid] = bv; si[tid] = bi;
  __syncthreads();
  for (int sN = 128; sN > 0; sN >>= 1){
    if (tid < sN){
      float ov = sv[tid+sN]; int oi = si[tid+sN];
      if (ov > sv[tid] || (ov == sv[tid] && oi < si[tid])){ sv[tid] = ov; si[tid] = oi; }
    }
    __syncthreads();
  }
  int best = si[0];
  const float* src = video + ((size_t)b * NT + best) * ND;
  o1[(size_t)b * ND + tid]       = src[tid];
  o1[(size_t)b * ND + tid + 256] = src[tid + 256];
}

extern "C" void kernel_launch(void* const* d_in, const int* in_sizes, int n_in,
                              void* d_out, int out_size, void* d_ws, size_t ws_size,
                              hipStream_t stream){
  const float* video = (const float*)d_in[0];
  const float* sent  = (const float*)d_in[1];
  const int*   lens  = (const int*)d_in[2];
  float* out0 = (float*)d_out;
  float* out1 = out0 + (size_t)NB*NB*NT;

  char* ws = (char*)d_ws;
  unsigned short* sb   = (unsigned short*)ws;             // 262144 B
  float* diagw = (float*)(ws + 262144);                   // 524288 B
  unsigned short* vb16 = (unsigned short*)(ws + 1048576); // 134217728 B

  k_sent   <<<NB/4,    256, 0, stream>>>(sent, sb);
  k_vnorm  <<<NB*NT/4, 256, 0, stream>>>(video, sent, vb16, diagw);
  k_gemm_sm<<<NB*4,    512, 0, stream>>>(sb, vb16, lens, out0);
  k_argmax <<<NB,      256, 0, stream>>>(video, lens, diagw, out1);
}